// Round 2
// baseline (144.265 us; speedup 1.0000x reference)
//
#include <hip/hip_runtime.h>

#define NB 2
#define NH 4
#define NS 512
#define ND 16
#define NF 32   // HID
// rows = B*H*S = 4096

// ---------------- Kernel 1: projections ----------------
// qp = q@Wq+bq ; kp = k@Wk+bk ; vp = v@Wv+bv
// hq row = [ hqA(32) = qp@A , hqB'(32) = qp@B + b1 ]
// hk row = [ hkA(32) = kp@A , hkB'(32) = kp@B + b1 ]
__global__ __launch_bounds__(64) void k_proj(
    const float* __restrict__ q, const float* __restrict__ kin, const float* __restrict__ v,
    const float* __restrict__ Wq, const float* __restrict__ bq,
    const float* __restrict__ Wk, const float* __restrict__ bk,
    const float* __restrict__ Wv, const float* __restrict__ bv,
    const float* __restrict__ N1, const float* __restrict__ b1,
    float* __restrict__ hq, float* __restrict__ hk, float* __restrict__ vp)
{
    __shared__ float wq_s[256], wk_s[256], wv_s[256], n1_s[1024];
    __shared__ float bq_s[16], bk_s[16], bv_s[16], b1_s[32];
    const int t = threadIdx.x;
    for (int i = t; i < 256; i += 64) { wq_s[i]=Wq[i]; wk_s[i]=Wk[i]; wv_s[i]=Wv[i]; }
    for (int i = t; i < 1024; i += 64) n1_s[i] = N1[i];
    if (t < 16) { bq_s[t]=bq[t]; bk_s[t]=bk[t]; bv_s[t]=bv[t]; }
    if (t < 32) b1_s[t] = b1[t];
    __syncthreads();

    const int r = blockIdx.x * 64 + t;   // 0..4095
    float qv[16], kv[16], vv[16];
    const float4* q4 = (const float4*)(q   + (size_t)r*16);
    const float4* k4 = (const float4*)(kin + (size_t)r*16);
    const float4* v4 = (const float4*)(v   + (size_t)r*16);
#pragma unroll
    for (int j = 0; j < 4; ++j) {
        float4 a = q4[j]; qv[4*j]=a.x; qv[4*j+1]=a.y; qv[4*j+2]=a.z; qv[4*j+3]=a.w;
        float4 b = k4[j]; kv[4*j]=b.x; kv[4*j+1]=b.y; kv[4*j+2]=b.z; kv[4*j+3]=b.w;
        float4 c = v4[j]; vv[4*j]=c.x; vv[4*j+1]=c.y; vv[4*j+2]=c.z; vv[4*j+3]=c.w;
    }

    float qp[16], kp[16], vpv[16];
#pragma unroll
    for (int d = 0; d < 16; ++d) { qp[d]=bq_s[d]; kp[d]=bk_s[d]; vpv[d]=bv_s[d]; }
#pragma unroll
    for (int e = 0; e < 16; ++e) {
#pragma unroll
        for (int d = 0; d < 16; ++d) {
            qp[d]  = fmaf(qv[e], wq_s[e*16+d], qp[d]);
            kp[d]  = fmaf(kv[e], wk_s[e*16+d], kp[d]);
            vpv[d] = fmaf(vv[e], wv_s[e*16+d], vpv[d]);
        }
    }
    // store vp
#pragma unroll
    for (int j = 0; j < 4; ++j) {
        float4 o; o.x=vpv[4*j]; o.y=vpv[4*j+1]; o.z=vpv[4*j+2]; o.w=vpv[4*j+3];
        ((float4*)(vp + (size_t)r*16))[j] = o;
    }

    float h[32];
    // hqA = qp @ A  (A = N1 rows 0..15)
#pragma unroll
    for (int f = 0; f < 32; ++f) h[f] = 0.f;
#pragma unroll
    for (int d = 0; d < 16; ++d)
#pragma unroll
        for (int f = 0; f < 32; ++f) h[f] = fmaf(qp[d], n1_s[d*32+f], h[f]);
#pragma unroll
    for (int j = 0; j < 8; ++j) {
        float4 o; o.x=h[4*j]; o.y=h[4*j+1]; o.z=h[4*j+2]; o.w=h[4*j+3];
        *(float4*)&hq[(size_t)r*64 + 4*j] = o;
    }
    // hqB' = qp @ B + b1  (B = N1 rows 16..31)
#pragma unroll
    for (int f = 0; f < 32; ++f) h[f] = b1_s[f];
#pragma unroll
    for (int d = 0; d < 16; ++d)
#pragma unroll
        for (int f = 0; f < 32; ++f) h[f] = fmaf(qp[d], n1_s[(16+d)*32+f], h[f]);
#pragma unroll
    for (int j = 0; j < 8; ++j) {
        float4 o; o.x=h[4*j]; o.y=h[4*j+1]; o.z=h[4*j+2]; o.w=h[4*j+3];
        *(float4*)&hq[(size_t)r*64 + 32 + 4*j] = o;
    }
    // hkA = kp @ A
#pragma unroll
    for (int f = 0; f < 32; ++f) h[f] = 0.f;
#pragma unroll
    for (int d = 0; d < 16; ++d)
#pragma unroll
        for (int f = 0; f < 32; ++f) h[f] = fmaf(kp[d], n1_s[d*32+f], h[f]);
#pragma unroll
    for (int j = 0; j < 8; ++j) {
        float4 o; o.x=h[4*j]; o.y=h[4*j+1]; o.z=h[4*j+2]; o.w=h[4*j+3];
        *(float4*)&hk[(size_t)r*64 + 4*j] = o;
    }
    // hkB' = kp @ B + b1
#pragma unroll
    for (int f = 0; f < 32; ++f) h[f] = b1_s[f];
#pragma unroll
    for (int d = 0; d < 16; ++d)
#pragma unroll
        for (int f = 0; f < 32; ++f) h[f] = fmaf(kp[d], n1_s[(16+d)*32+f], h[f]);
#pragma unroll
    for (int j = 0; j < 8; ++j) {
        float4 o; o.x=h[4*j]; o.y=h[4*j+1]; o.z=h[4*j+2]; o.w=h[4*j+3];
        *(float4*)&hk[(size_t)r*64 + 32 + 4*j] = o;
    }
}

// ---------------- Kernel 2: scores + softmax -> attn ----------------
// grid: 8 (b,h) * 32 q-tiles = 256 blocks, 512 threads (8 waves).
// Each thread owns one k (tid = k); hkA/hkB' live in registers.
// score(q,k) = sum_f relu(hqA[q][f]+hkB'[k][f])*n2[f]
//            + sum_f relu(hkA[k][f]+hqB'[q][f])*n2[f] + 2*b2 + mask*(-1e9)
__global__ __launch_bounds__(512) void k_scores(
    const float* __restrict__ hq, const float* __restrict__ hk,
    const float* __restrict__ N2, const float* __restrict__ b2,
    const float* __restrict__ mask, float* __restrict__ attn)
{
    const int bh  = blockIdx.x >> 5;
    const int q0  = (blockIdx.x & 31) << 4;
    const int tid = threadIdx.x;
    const int wave = tid >> 6, lane = tid & 63;
    const int k = tid;                       // 0..511
    const int rk = bh * NS + k;

    float hkA_l[32], hkB_l[32], n2_l[32];
    const float4* hk4 = (const float4*)(hk + (size_t)rk*64);
#pragma unroll
    for (int j = 0; j < 8; ++j) {
        float4 a = hk4[j];     hkA_l[4*j]=a.x; hkA_l[4*j+1]=a.y; hkA_l[4*j+2]=a.z; hkA_l[4*j+3]=a.w;
        float4 b = hk4[8+j];   hkB_l[4*j]=b.x; hkB_l[4*j+1]=b.y; hkB_l[4*j+2]=b.z; hkB_l[4*j+3]=b.w;
    }
#pragma unroll
    for (int f = 0; f < 32; ++f) n2_l[f] = N2[f];
    const float b2v = 2.0f * b2[0];
    const int b = bh >> 2;   // H = 4
    const float* mbase = mask + (size_t)b * NS * NS;

    __shared__ float red[16];  // [0..7] wave max, [8..15] wave sum

    for (int qi = 0; qi < 16; ++qi) {
        const int qg = q0 + qi;
        const int rq = bh * NS + qg;
        const float* hqr = hq + (size_t)rq * 64;   // uniform address -> scalar loads

        float s0 = b2v, s1 = 0.f, s2 = 0.f, s3 = 0.f;
#pragma unroll
        for (int f4 = 0; f4 < 8; ++f4) {
#pragma unroll
            for (int j = 0; j < 4; ++j) {
                const int f = 4*f4 + j;
                float t1 = hqr[f]      + hkB_l[f];
                float t2 = hqr[32 + f] + hkA_l[f];
                float n2f = n2_l[f];
                float acc = fmaf(fmaxf(t1, 0.f), n2f, fmaxf(t2, 0.f) * n2f);
                if (j == 0) s0 += acc; else if (j == 1) s1 += acc;
                else if (j == 2) s2 += acc; else s3 += acc;
            }
        }
        float s = (s0 + s1) + (s2 + s3);
        s = fmaf(mbase[(size_t)qg * NS + k], -1e9f, s);

        // block softmax over 512 k
        float m = s;
#pragma unroll
        for (int off = 32; off > 0; off >>= 1) m = fmaxf(m, __shfl_xor(m, off));
        if (lane == 0) red[wave] = m;
        __syncthreads();
        float bm = red[0];
#pragma unroll
        for (int w = 1; w < 8; ++w) bm = fmaxf(bm, red[w]);
        float e = __expf(s - bm);
        float ss = e;
#pragma unroll
        for (int off = 32; off > 0; off >>= 1) ss += __shfl_xor(ss, off);
        if (lane == 0) red[8 + wave] = ss;
        __syncthreads();
        float tot = red[8];
#pragma unroll
        for (int w = 1; w < 8; ++w) tot += red[8 + w];

        attn[(size_t)rq * NS + k] = e / tot;
    }
}

// ---------------- Kernel 3: out = (attn @ vp) @ Wo + bo ----------------
// grid 256 (bh x 32 q-tiles), 256 threads: thread = (qi, d)
__global__ __launch_bounds__(256) void k_av(
    const float* __restrict__ attn, const float* __restrict__ vp,
    const float* __restrict__ Wo, const float* __restrict__ bo,
    float* __restrict__ out)
{
    __shared__ float attn_s[16 * 516];   // padded row 516 -> conflict-free per-qi
    __shared__ float vp_s[512 * 17];     // padded row 17
    __shared__ float wo_s[256];
    __shared__ float bo_s[16];
    __shared__ float ov_s[256];

    const int bh = blockIdx.x >> 5;
    const int q0 = (blockIdx.x & 31) << 4;
    const int tid = threadIdx.x;

    const float4* ag = (const float4*)(attn + ((size_t)(bh * NS + q0)) * NS);
#pragma unroll
    for (int it = 0; it < 8; ++it) {
        int j = tid + 256 * it;          // 0..2047 float4s (16 rows x 128)
        float4 a = ag[j];
        int qi2 = j >> 7, c4 = j & 127;
        *(float4*)&attn_s[qi2 * 516 + 4 * c4] = a;
    }
    const float4* vg = (const float4*)(vp + (size_t)bh * NS * 16);
#pragma unroll
    for (int it = 0; it < 8; ++it) {
        int j = tid + 256 * it;          // 0..2047 float4s (512 rows x 4)
        float4 w = vg[j];
        int kr = j >> 2, d0 = (j & 3) * 4;
        vp_s[kr*17 + d0] = w.x; vp_s[kr*17 + d0+1] = w.y;
        vp_s[kr*17 + d0+2] = w.z; vp_s[kr*17 + d0+3] = w.w;
    }
    wo_s[tid & 255] = Wo[tid & 255];
    if (tid < 16) bo_s[tid] = bo[tid];
    __syncthreads();

    const int qi = tid >> 4, d = tid & 15;
    float ov0 = 0.f, ov1 = 0.f;
#pragma unroll 4
    for (int k4 = 0; k4 < 128; ++k4) {
        float4 a = *(const float4*)&attn_s[qi * 516 + 4 * k4];
        int kb = 4 * k4;
        ov0 = fmaf(a.x, vp_s[(kb    ) * 17 + d], ov0);
        ov1 = fmaf(a.y, vp_s[(kb + 1) * 17 + d], ov1);
        ov0 = fmaf(a.z, vp_s[(kb + 2) * 17 + d], ov0);
        ov1 = fmaf(a.w, vp_s[(kb + 3) * 17 + d], ov1);
    }
    ov_s[qi * 16 + d] = ov0 + ov1;
    __syncthreads();

    float res = bo_s[d];
#pragma unroll
    for (int e = 0; e < 16; ++e)
        res = fmaf(ov_s[qi * 16 + e], wo_s[e * 16 + d], res);
    out[((size_t)(bh * NS + q0 + qi)) * 16 + d] = res;
}

extern "C" void kernel_launch(void* const* d_in, const int* in_sizes, int n_in,
                              void* d_out, int out_size, void* d_ws, size_t ws_size,
                              hipStream_t stream)
{
    const float* v    = (const float*)d_in[0];
    const float* k    = (const float*)d_in[1];
    const float* q    = (const float*)d_in[2];
    const float* mask = (const float*)d_in[3];
    const float* Wq   = (const float*)d_in[4];
    const float* bq   = (const float*)d_in[5];
    const float* Wk   = (const float*)d_in[6];
    const float* bk   = (const float*)d_in[7];
    const float* Wv   = (const float*)d_in[8];
    const float* bv   = (const float*)d_in[9];
    const float* Wo   = (const float*)d_in[10];
    const float* bo   = (const float*)d_in[11];
    const float* N1   = (const float*)d_in[12];
    const float* b1   = (const float*)d_in[13];
    const float* N2   = (const float*)d_in[14];
    const float* b2   = (const float*)d_in[15];

    float* out  = (float*)d_out;                   // 65536 floats
    float* attn = out + (size_t)NB*NH*NS*ND;       // 2097152 floats

    float* hq = (float*)d_ws;                      // 4096*64
    float* hk = hq + (size_t)4096 * 64;            // 4096*64
    float* vp = hk + (size_t)4096 * 64;            // 4096*16

    k_proj  <<<64, 64, 0, stream>>>(q, k, v, Wq, bq, Wk, bk, Wv, bv, N1, b1, hq, hk, vp);
    k_scores<<<256, 512, 0, stream>>>(hq, hk, N2, b2, mask, attn);
    k_av    <<<256, 256, 0, stream>>>(attn, vp, Wo, bo, out);
}

// Round 3
// 83.561 us; speedup vs baseline: 1.7265x; 1.7265x over previous
//
#include <hip/hip_runtime.h>

#define NB 2
#define NH 4
#define NS 512
#define ND 16
#define NF 32   // HID
// rows = B*H*S = 4096
// hq/hk layout: transposed [bh][f 0..63][s 0..511]; f<32 = @A part, f>=32 = @B+b1 part.

// ---------------- Kernel 1: projections ----------------
// 32 blocks x 128 threads; block handles 128 consecutive rows of one (b,h).
__global__ __launch_bounds__(128) void k_proj(
    const float* __restrict__ q, const float* __restrict__ kin, const float* __restrict__ v,
    const float* __restrict__ Wq, const float* __restrict__ bq,
    const float* __restrict__ Wk, const float* __restrict__ bk,
    const float* __restrict__ Wv, const float* __restrict__ bv,
    const float* __restrict__ N1, const float* __restrict__ b1,
    float* __restrict__ hq, float* __restrict__ hk, float* __restrict__ vp)
{
    __shared__ float wq_s[256], wk_s[256], wv_s[256], n1_s[1024];
    __shared__ float bq_s[16], bk_s[16], bv_s[16], b1_s[32];
    const int t = threadIdx.x;
    for (int i = t; i < 256; i += 128) { wq_s[i]=Wq[i]; wk_s[i]=Wk[i]; wv_s[i]=Wv[i]; }
    for (int i = t; i < 1024; i += 128) n1_s[i] = N1[i];
    if (t < 16) { bq_s[t]=bq[t]; bk_s[t]=bk[t]; bv_s[t]=bv[t]; }
    if (t < 32) b1_s[t] = b1[t];
    __syncthreads();

    const int bh = blockIdx.x >> 2;
    const int s  = ((blockIdx.x & 3) << 7) + t;   // 0..511 within this bh
    const int r  = bh * NS + s;                   // global row

    float qv[16], kv[16], vv[16];
    const float4* q4 = (const float4*)(q   + (size_t)r*16);
    const float4* k4 = (const float4*)(kin + (size_t)r*16);
    const float4* v4 = (const float4*)(v   + (size_t)r*16);
#pragma unroll
    for (int j = 0; j < 4; ++j) {
        float4 a = q4[j]; qv[4*j]=a.x; qv[4*j+1]=a.y; qv[4*j+2]=a.z; qv[4*j+3]=a.w;
        float4 b = k4[j]; kv[4*j]=b.x; kv[4*j+1]=b.y; kv[4*j+2]=b.z; kv[4*j+3]=b.w;
        float4 c = v4[j]; vv[4*j]=c.x; vv[4*j+1]=c.y; vv[4*j+2]=c.z; vv[4*j+3]=c.w;
    }

    float* hqb = hq + (size_t)bh * 32768 + s;
    float* hkb = hk + (size_t)bh * 32768 + s;

    // ---- q path ----
    {
        float qp[16];
#pragma unroll
        for (int d = 0; d < 16; ++d) qp[d] = bq_s[d];
#pragma unroll
        for (int e = 0; e < 16; ++e)
#pragma unroll
            for (int d = 0; d < 16; ++d) qp[d] = fmaf(qv[e], wq_s[e*16+d], qp[d]);

        float hA[32], hB[32];
#pragma unroll
        for (int f = 0; f < 32; ++f) { hA[f] = 0.f; hB[f] = b1_s[f]; }
#pragma unroll
        for (int d = 0; d < 16; ++d) {
#pragma unroll
            for (int f = 0; f < 32; ++f) {
                hA[f] = fmaf(qp[d], n1_s[d*32+f],      hA[f]);
                hB[f] = fmaf(qp[d], n1_s[(16+d)*32+f], hB[f]);
            }
        }
#pragma unroll
        for (int f = 0; f < 32; ++f) hqb[(size_t)f * NS] = hA[f];          // coalesced over s
#pragma unroll
        for (int f = 0; f < 32; ++f) hqb[(size_t)(32+f) * NS] = hB[f];
    }

    // ---- k path ----
    {
        float kp[16];
#pragma unroll
        for (int d = 0; d < 16; ++d) kp[d] = bk_s[d];
#pragma unroll
        for (int e = 0; e < 16; ++e)
#pragma unroll
            for (int d = 0; d < 16; ++d) kp[d] = fmaf(kv[e], wk_s[e*16+d], kp[d]);

        float hA[32], hB[32];
#pragma unroll
        for (int f = 0; f < 32; ++f) { hA[f] = 0.f; hB[f] = b1_s[f]; }
#pragma unroll
        for (int d = 0; d < 16; ++d) {
#pragma unroll
            for (int f = 0; f < 32; ++f) {
                hA[f] = fmaf(kp[d], n1_s[d*32+f],      hA[f]);
                hB[f] = fmaf(kp[d], n1_s[(16+d)*32+f], hB[f]);
            }
        }
#pragma unroll
        for (int f = 0; f < 32; ++f) hkb[(size_t)f * NS] = hA[f];
#pragma unroll
        for (int f = 0; f < 32; ++f) hkb[(size_t)(32+f) * NS] = hB[f];
    }

    // ---- v path (natural [row][d] layout, consumed by k_av float4 staging) ----
    {
        float vpv[16];
#pragma unroll
        for (int d = 0; d < 16; ++d) vpv[d] = bv_s[d];
#pragma unroll
        for (int e = 0; e < 16; ++e)
#pragma unroll
            for (int d = 0; d < 16; ++d) vpv[d] = fmaf(vv[e], wv_s[e*16+d], vpv[d]);
#pragma unroll
        for (int j = 0; j < 4; ++j) {
            float4 o; o.x=vpv[4*j]; o.y=vpv[4*j+1]; o.z=vpv[4*j+2]; o.w=vpv[4*j+3];
            ((float4*)(vp + (size_t)r*16))[j] = o;
        }
    }
}

// ---------------- Kernel 2: scores + softmax -> attn ----------------
// grid: 8 (b,h) * 32 q-tiles = 256 blocks, 512 threads (8 waves).
// Thread owns one k; hkA/hkB' loaded coalesced from transposed layout into regs.
// hq slice for the 16 q rows staged in LDS, read via uniform broadcast.
__global__ __launch_bounds__(512) void k_scores(
    const float* __restrict__ hq, const float* __restrict__ hk,
    const float* __restrict__ N2, const float* __restrict__ b2,
    const float* __restrict__ mask, float* __restrict__ attn)
{
    const int bh  = blockIdx.x >> 5;
    const int q0  = (blockIdx.x & 31) << 4;
    const int tid = threadIdx.x;
    const int wave = tid >> 6, lane = tid & 63;
    const int k = tid;                       // 0..511
    const size_t base = (size_t)bh * 32768;

    __shared__ float hq_s[16 * 68];          // [qi][f 0..63], pad 68
    __shared__ float red[16];                // [0..7] wave max, [8..15] wave sum

    float hkA_l[32], hkB_l[32], n2_l[32];
#pragma unroll
    for (int f = 0; f < 32; ++f) hkA_l[f] = hk[base + (size_t)f * NS + k];        // coalesced
#pragma unroll
    for (int f = 0; f < 32; ++f) hkB_l[f] = hk[base + (size_t)(32+f) * NS + k];   // coalesced

    for (int i = tid; i < 1024; i += 512) {
        int f = i >> 4, qi = i & 15;
        hq_s[qi * 68 + f] = hq[base + (size_t)f * NS + q0 + qi];
    }
#pragma unroll
    for (int f = 0; f < 32; ++f) n2_l[f] = N2[f];
    const float b2v = 2.0f * b2[0];
    const int b = bh >> 2;   // H = 4
    const float* mbase = mask + (size_t)b * NS * NS;
    __syncthreads();

    for (int qi = 0; qi < 16; ++qi) {
        const int qg = q0 + qi;
        const int rq = bh * NS + qg;
        const float* hqr = &hq_s[qi * 68];   // uniform -> LDS broadcast

        float s0 = b2v, s1 = 0.f, s2 = 0.f, s3 = 0.f;
#pragma unroll
        for (int f4 = 0; f4 < 8; ++f4) {
#pragma unroll
            for (int j = 0; j < 4; ++j) {
                const int f = 4*f4 + j;
                float t1 = hqr[f]      + hkB_l[f];
                float t2 = hqr[32 + f] + hkA_l[f];
                float n2f = n2_l[f];
                float acc = fmaf(fmaxf(t1, 0.f), n2f, fmaxf(t2, 0.f) * n2f);
                if (j == 0) s0 += acc; else if (j == 1) s1 += acc;
                else if (j == 2) s2 += acc; else s3 += acc;
            }
        }
        float s = (s0 + s1) + (s2 + s3);
        s = fmaf(mbase[(size_t)qg * NS + k], -1e9f, s);

        // block softmax over 512 k
        float m = s;
#pragma unroll
        for (int off = 32; off > 0; off >>= 1) m = fmaxf(m, __shfl_xor(m, off));
        if (lane == 0) red[wave] = m;
        __syncthreads();
        float bm = red[0];
#pragma unroll
        for (int w = 1; w < 8; ++w) bm = fmaxf(bm, red[w]);
        float e = __expf(s - bm);
        float ss = e;
#pragma unroll
        for (int off = 32; off > 0; off >>= 1) ss += __shfl_xor(ss, off);
        if (lane == 0) red[8 + wave] = ss;
        __syncthreads();
        float tot = red[8];
#pragma unroll
        for (int w = 1; w < 8; ++w) tot += red[8 + w];

        attn[(size_t)rq * NS + k] = e / tot;
    }
}

// ---------------- Kernel 3: out = (attn @ vp) @ Wo + bo ----------------
// grid 256 (bh x 32 q-tiles), 256 threads: thread = (qi, d)
__global__ __launch_bounds__(256) void k_av(
    const float* __restrict__ attn, const float* __restrict__ vp,
    const float* __restrict__ Wo, const float* __restrict__ bo,
    float* __restrict__ out)
{
    __shared__ float attn_s[16 * 516];   // padded row 516
    __shared__ float vp_s[512 * 17];     // padded row 17
    __shared__ float wo_s[256];
    __shared__ float bo_s[16];
    __shared__ float ov_s[256];

    const int bh = blockIdx.x >> 5;
    const int q0 = (blockIdx.x & 31) << 4;
    const int tid = threadIdx.x;

    const float4* ag = (const float4*)(attn + ((size_t)(bh * NS + q0)) * NS);
#pragma unroll
    for (int it = 0; it < 8; ++it) {
        int j = tid + 256 * it;          // 0..2047 float4s (16 rows x 128)
        float4 a = ag[j];
        int qi2 = j >> 7, c4 = j & 127;
        *(float4*)&attn_s[qi2 * 516 + 4 * c4] = a;
    }
    const float4* vg = (const float4*)(vp + (size_t)bh * NS * 16);
#pragma unroll
    for (int it = 0; it < 8; ++it) {
        int j = tid + 256 * it;          // 0..2047 float4s (512 rows x 4)
        float4 w = vg[j];
        int kr = j >> 2, d0 = (j & 3) * 4;
        vp_s[kr*17 + d0] = w.x; vp_s[kr*17 + d0+1] = w.y;
        vp_s[kr*17 + d0+2] = w.z; vp_s[kr*17 + d0+3] = w.w;
    }
    wo_s[tid & 255] = Wo[tid & 255];
    if (tid < 16) bo_s[tid] = bo[tid];
    __syncthreads();

    const int qi = tid >> 4, d = tid & 15;
    float ov0 = 0.f, ov1 = 0.f;
#pragma unroll 4
    for (int k4 = 0; k4 < 128; ++k4) {
        float4 a = *(const float4*)&attn_s[qi * 516 + 4 * k4];
        int kb = 4 * k4;
        ov0 = fmaf(a.x, vp_s[(kb    ) * 17 + d], ov0);
        ov1 = fmaf(a.y, vp_s[(kb + 1) * 17 + d], ov1);
        ov0 = fmaf(a.z, vp_s[(kb + 2) * 17 + d], ov0);
        ov1 = fmaf(a.w, vp_s[(kb + 3) * 17 + d], ov1);
    }
    ov_s[qi * 16 + d] = ov0 + ov1;
    __syncthreads();

    float res = bo_s[d];
#pragma unroll
    for (int e = 0; e < 16; ++e)
        res = fmaf(ov_s[qi * 16 + e], wo_s[e * 16 + d], res);
    out[((size_t)(bh * NS + q0 + qi)) * 16 + d] = res;
}

extern "C" void kernel_launch(void* const* d_in, const int* in_sizes, int n_in,
                              void* d_out, int out_size, void* d_ws, size_t ws_size,
                              hipStream_t stream)
{
    const float* v    = (const float*)d_in[0];
    const float* k    = (const float*)d_in[1];
    const float* q    = (const float*)d_in[2];
    const float* mask = (const float*)d_in[3];
    const float* Wq   = (const float*)d_in[4];
    const float* bq   = (const float*)d_in[5];
    const float* Wk   = (const float*)d_in[6];
    const float* bk   = (const float*)d_in[7];
    const float* Wv   = (const float*)d_in[8];
    const float* bv   = (const float*)d_in[9];
    const float* Wo   = (const float*)d_in[10];
    const float* bo   = (const float*)d_in[11];
    const float* N1   = (const float*)d_in[12];
    const float* b1   = (const float*)d_in[13];
    const float* N2   = (const float*)d_in[14];
    const float* b2   = (const float*)d_in[15];

    float* out  = (float*)d_out;                   // 65536 floats
    float* attn = out + (size_t)NB*NH*NS*ND;       // 2097152 floats

    float* hq = (float*)d_ws;                      // 8*64*512 = 262144 floats
    float* hk = hq + (size_t)8 * 32768;            // 262144 floats
    float* vp = hk + (size_t)8 * 32768;            // 65536 floats

    k_proj  <<<32, 128, 0, stream>>>(q, k, v, Wq, bq, Wk, bk, Wv, bv, N1, b1, hq, hk, vp);
    k_scores<<<256, 512, 0, stream>>>(hq, hk, N2, b2, mask, attn);
    k_av    <<<256, 256, 0, stream>>>(attn, vp, Wo, bo, out);
}

// Round 5
// 42.267 us; speedup vs baseline: 3.4131x; 1.9770x over previous
//
#include <hip/hip_runtime.h>

#define NB 2
#define NH 4
#define NS 512
#define ND 16
#define NF 32   // HID
// workspace layouts:
//   hq, hk : [bh][f 0..63][s 0..511]   (f<32: @A part, f>=32: @B+b1 part)
//   vpt    : [bh][d 0..15][s 0..511]   (transposed vp)

// ---------------- Kernel 1: fused projections ----------------
// hq = q @ (Wq@[A|B]) + (bq@[A|B] + [0|b1]);  hk likewise with Wk;  vpt = (v@Wv+bv)^T
// grid 80 = 8 bh * 2 s-chunks * 5 jobs; 256 threads; job: 0 q-A, 1 q-B, 2 k-A, 3 k-B, 4 v.
__global__ __launch_bounds__(256) void k_proj(
    const float* __restrict__ q, const float* __restrict__ kin, const float* __restrict__ v,
    const float* __restrict__ Wq, const float* __restrict__ bq,
    const float* __restrict__ Wk, const float* __restrict__ bk,
    const float* __restrict__ Wv, const float* __restrict__ bv,
    const float* __restrict__ N1, const float* __restrict__ b1,
    float* __restrict__ hq, float* __restrict__ hk, float* __restrict__ vpt)
{
    __shared__ float m_s[16 * 32];   // fused matrix chunk [e][f]
    __shared__ float c_s[32];        // fused bias chunk

    const int bid = blockIdx.x;
    const int job = bid % 5;
    const int sc  = (bid / 5) & 1;
    const int bh  = bid / 10;
    const int t   = threadIdx.x;

    const float* W    = (job < 2) ? Wq : (job < 4 ? Wk : Wv);
    const float* bias = (job < 2) ? bq : (job < 4 ? bk : bv);
    const float* x    = (job < 2) ? q  : (job < 4 ? kin : v);

    if (job < 4) {
        const int noff = (job & 1) * 16;         // A rows 0..15, B rows 16..31 of N1
        for (int i = t; i < 512; i += 256) {
            int e = i >> 5, f = i & 31;
            float m = 0.f;
#pragma unroll
            for (int d = 0; d < 16; ++d)
                m = fmaf(W[e * 16 + d], N1[(noff + d) * 32 + f], m);
            m_s[i] = m;
        }
        if (t < 32) {
            float c = (job & 1) ? b1[t] : 0.f;
#pragma unroll
            for (int d = 0; d < 16; ++d)
                c = fmaf(bias[d], N1[(noff + d) * 32 + t], c);
            c_s[t] = c;
        }
    } else {
        int e = t >> 4, d = t & 15;              // t<256 covers all 256
        m_s[e * 32 + d] = W[e * 16 + d];
        if (t < 16) c_s[t] = bias[t];
    }
    __syncthreads();

    const int s = sc * 256 + t;                  // 0..511 within bh
    const int r = bh * NS + s;

    float xv[16];
    const float4* x4 = (const float4*)(x + (size_t)r * 16);
#pragma unroll
    for (int j = 0; j < 4; ++j) {
        float4 a = x4[j];
        xv[4*j] = a.x; xv[4*j+1] = a.y; xv[4*j+2] = a.z; xv[4*j+3] = a.w;
    }

    if (job < 4) {
        float* outb = ((job < 2) ? hq : hk) + (size_t)bh * 32768 + (size_t)(job & 1) * 16384;
        float h[32];
#pragma unroll
        for (int f = 0; f < 32; ++f) h[f] = c_s[f];
#pragma unroll
        for (int e = 0; e < 16; ++e)
#pragma unroll
            for (int f = 0; f < 32; ++f)
                h[f] = fmaf(xv[e], m_s[e * 32 + f], h[f]);
#pragma unroll
        for (int f = 0; f < 32; ++f)
            outb[(size_t)f * NS + s] = h[f];     // coalesced over s
    } else {
        float* outb = vpt + (size_t)bh * 8192;
        float h[16];
#pragma unroll
        for (int d = 0; d < 16; ++d) h[d] = c_s[d];
#pragma unroll
        for (int e = 0; e < 16; ++e)
#pragma unroll
            for (int d = 0; d < 16; ++d)
                h[d] = fmaf(xv[e], m_s[e * 32 + d], h[d]);
#pragma unroll
        for (int d = 0; d < 16; ++d)
            outb[(size_t)d * NS + s] = h[d];     // coalesced over s
    }
}

// ---------------- Kernel 2: scores + softmax -> attn ----------------
// grid: 8 (b,h) * 32 q-tiles = 256 blocks, 512 threads (8 waves).
// Thread owns one k; hkA/hkB' loaded coalesced from transposed layout into regs.
// hq slice for the 16 q rows staged in LDS, read via uniform broadcast.
__global__ __launch_bounds__(512) void k_scores(
    const float* __restrict__ hq, const float* __restrict__ hk,
    const float* __restrict__ N2, const float* __restrict__ b2,
    const float* __restrict__ mask, float* __restrict__ attn)
{
    const int bh  = blockIdx.x >> 5;
    const int q0  = (blockIdx.x & 31) << 4;
    const int tid = threadIdx.x;
    const int wave = tid >> 6, lane = tid & 63;
    const int k = tid;                       // 0..511
    const size_t base = (size_t)bh * 32768;

    __shared__ float hq_s[16 * 68];          // [qi][f 0..63], pad 68
    __shared__ float red[16];                // [0..7] wave max, [8..15] wave sum

    float hkA_l[32], hkB_l[32], n2_l[32];
#pragma unroll
    for (int f = 0; f < 32; ++f) hkA_l[f] = hk[base + (size_t)f * NS + k];        // coalesced
#pragma unroll
    for (int f = 0; f < 32; ++f) hkB_l[f] = hk[base + (size_t)(32+f) * NS + k];   // coalesced

    for (int i = tid; i < 1024; i += 512) {
        int f = i >> 4, qi = i & 15;
        hq_s[qi * 68 + f] = hq[base + (size_t)f * NS + q0 + qi];
    }
#pragma unroll
    for (int f = 0; f < 32; ++f) n2_l[f] = N2[f];
    const float b2v = 2.0f * b2[0];
    const int b = bh >> 2;   // H = 4
    const float* mbase = mask + (size_t)b * NS * NS;
    __syncthreads();

    for (int qi = 0; qi < 16; ++qi) {
        const int qg = q0 + qi;
        const int rq = bh * NS + qg;
        const float* hqr = &hq_s[qi * 68];   // uniform -> LDS broadcast

        float s0 = b2v, s1 = 0.f, s2 = 0.f, s3 = 0.f;
#pragma unroll
        for (int f4 = 0; f4 < 8; ++f4) {
#pragma unroll
            for (int j = 0; j < 4; ++j) {
                const int f = 4*f4 + j;
                float t1 = hqr[f]      + hkB_l[f];
                float t2 = hqr[32 + f] + hkA_l[f];
                float a  = fmaxf(t1, 0.f) + fmaxf(t2, 0.f);
                float n2f = n2_l[f];
                if (j == 0) s0 = fmaf(n2f, a, s0); else if (j == 1) s1 = fmaf(n2f, a, s1);
                else if (j == 2) s2 = fmaf(n2f, a, s2); else s3 = fmaf(n2f, a, s3);
            }
        }
        float s = (s0 + s1) + (s2 + s3);
        s = fmaf(mbase[(size_t)qg * NS + k], -1e9f, s);

        // block softmax over 512 k
        float m = s;
#pragma unroll
        for (int off = 32; off > 0; off >>= 1) m = fmaxf(m, __shfl_xor(m, off));
        if (lane == 0) red[wave] = m;
        __syncthreads();
        float bm = red[0];
#pragma unroll
        for (int w = 1; w < 8; ++w) bm = fmaxf(bm, red[w]);
        float e = __expf(s - bm);
        float ss = e;
#pragma unroll
        for (int off = 32; off > 0; off >>= 1) ss += __shfl_xor(ss, off);
        if (lane == 0) red[8 + wave] = ss;
        __syncthreads();
        float tot = red[8];
#pragma unroll
        for (int w = 1; w < 8; ++w) tot += red[8 + w];

        attn[(size_t)rq * NS + k] = e / tot;
    }
}

// ---------------- Kernel 3: out = (attn @ vp) @ Wo + bo ----------------
// grid 256 (bh x 32 q-tiles), 256 threads: thread = (qi, d)
__global__ __launch_bounds__(256) void k_av(
    const float* __restrict__ attn, const float* __restrict__ vpt,
    const float* __restrict__ Wo, const float* __restrict__ bo,
    float* __restrict__ out)
{
    __shared__ float attn_s[16 * 516];   // padded row 516
    __shared__ float vp_s[512 * 17];     // padded row 17
    __shared__ float wo_s[256];
    __shared__ float bo_s[16];
    __shared__ float ov_s[256];

    const int bh = blockIdx.x >> 5;
    const int q0 = (blockIdx.x & 31) << 4;
    const int tid = threadIdx.x;

    const float4* ag = (const float4*)(attn + ((size_t)(bh * NS + q0)) * NS);
#pragma unroll
    for (int it = 0; it < 8; ++it) {
        int j = tid + 256 * it;          // 0..2047 float4s (16 rows x 128)
        float4 a = ag[j];
        int qi2 = j >> 7, c4 = j & 127;
        *(float4*)&attn_s[qi2 * 516 + 4 * c4] = a;
    }
    // stage vpt (transposed [d][s]) into vp_s[k][d] (row 17): coalesced global reads,
    // stride-17 LDS writes = 2-way bank alias (free per m136).
    const float* vg = vpt + (size_t)bh * 8192;
#pragma unroll
    for (int it = 0; it < 32; ++it) {
        int j = tid + 256 * it;          // 0..8191 floats; d = j>>9 (0..15), k = j&511
        float w = vg[j];
        int d = j >> 9, kk = j & 511;
        vp_s[kk * 17 + d] = w;
    }
    wo_s[tid] = Wo[tid];
    if (tid < 16) bo_s[tid] = bo[tid];
    __syncthreads();

    const int qi = tid >> 4, d = tid & 15;
    float ov0 = 0.f, ov1 = 0.f;
#pragma unroll 4
    for (int k4 = 0; k4 < 128; ++k4) {
        float4 a = *(const float4*)&attn_s[qi * 516 + 4 * k4];
        int kb = 4 * k4;
        ov0 = fmaf(a.x, vp_s[(kb    ) * 17 + d], ov0);
        ov1 = fmaf(a.y, vp_s[(kb + 1) * 17 + d], ov1);
        ov0 = fmaf(a.z, vp_s[(kb + 2) * 17 + d], ov0);
        ov1 = fmaf(a.w, vp_s[(kb + 3) * 17 + d], ov1);
    }
    ov_s[qi * 16 + d] = ov0 + ov1;
    __syncthreads();

    float res = bo_s[d];
#pragma unroll
    for (int e = 0; e < 16; ++e)
        res = fmaf(ov_s[qi * 16 + e], wo_s[e * 16 + d], res);
    out[((size_t)(bh * NS + q0 + qi)) * 16 + d] = res;
}

extern "C" void kernel_launch(void* const* d_in, const int* in_sizes, int n_in,
                              void* d_out, int out_size, void* d_ws, size_t ws_size,
                              hipStream_t stream)
{
    const float* v    = (const float*)d_in[0];
    const float* k    = (const float*)d_in[1];
    const float* q    = (const float*)d_in[2];
    const float* mask = (const float*)d_in[3];
    const float* Wq   = (const float*)d_in[4];
    const float* bq   = (const float*)d_in[5];
    const float* Wk   = (const float*)d_in[6];
    const float* bk   = (const float*)d_in[7];
    const float* Wv   = (const float*)d_in[8];
    const float* bv   = (const float*)d_in[9];
    const float* Wo   = (const float*)d_in[10];
    const float* bo   = (const float*)d_in[11];
    const float* N1   = (const float*)d_in[12];
    const float* b1   = (const float*)d_in[13];
    const float* N2   = (const float*)d_in[14];
    const float* b2   = (const float*)d_in[15];

    float* out  = (float*)d_out;                   // 65536 floats
    float* attn = out + (size_t)NB*NH*NS*ND;       // 2097152 floats

    float* hq  = (float*)d_ws;                     // 8*64*512 = 262144 floats
    float* hk  = hq + (size_t)8 * 32768;           // 262144 floats
    float* vpt = hk + (size_t)8 * 32768;           // 8*16*512 = 65536 floats

    k_proj  <<<80, 256, 0, stream>>>(q, k, v, Wq, bq, Wk, bk, Wv, bv, N1, b1, hq, hk, vpt);
    k_scores<<<256, 512, 0, stream>>>(hq, hk, N2, b2, mask, attn);
    k_av    <<<256, 256, 0, stream>>>(attn, vpt, Wo, bo, out);
}

// Round 6
// 38.070 us; speedup vs baseline: 3.7895x; 1.1103x over previous
//
#include <hip/hip_runtime.h>

#define NB 2
#define NH 4
#define NS 512
#define ND 16
#define NF 32
// workspace layouts:
//   hq, hk : [bh][f 0..63][s 0..511]   (f<32: @A part, f>=32: @B+b1 part)
//   vpt    : [bh][d 0..15][s 0..511]   (transposed vp)

// ---------------- Kernel 1: fused projections (unchanged from R5) ----------------
__global__ __launch_bounds__(256) void k_proj(
    const float* __restrict__ q, const float* __restrict__ kin, const float* __restrict__ v,
    const float* __restrict__ Wq, const float* __restrict__ bq,
    const float* __restrict__ Wk, const float* __restrict__ bk,
    const float* __restrict__ Wv, const float* __restrict__ bv,
    const float* __restrict__ N1, const float* __restrict__ b1,
    float* __restrict__ hq, float* __restrict__ hk, float* __restrict__ vpt)
{
    __shared__ float m_s[16 * 32];
    __shared__ float c_s[32];

    const int bid = blockIdx.x;
    const int job = bid % 5;
    const int sc  = (bid / 5) & 1;
    const int bh  = bid / 10;
    const int t   = threadIdx.x;

    const float* W    = (job < 2) ? Wq : (job < 4 ? Wk : Wv);
    const float* bias = (job < 2) ? bq : (job < 4 ? bk : bv);
    const float* x    = (job < 2) ? q  : (job < 4 ? kin : v);

    if (job < 4) {
        const int noff = (job & 1) * 16;
        for (int i = t; i < 512; i += 256) {
            int e = i >> 5, f = i & 31;
            float m = 0.f;
#pragma unroll
            for (int d = 0; d < 16; ++d)
                m = fmaf(W[e * 16 + d], N1[(noff + d) * 32 + f], m);
            m_s[i] = m;
        }
        if (t < 32) {
            float c = (job & 1) ? b1[t] : 0.f;
#pragma unroll
            for (int d = 0; d < 16; ++d)
                c = fmaf(bias[d], N1[(noff + d) * 32 + t], c);
            c_s[t] = c;
        }
    } else {
        int e = t >> 4, d = t & 15;
        m_s[e * 32 + d] = W[e * 16 + d];
        if (t < 16) c_s[t] = bias[t];
    }
    __syncthreads();

    const int s = sc * 256 + t;
    const int r = bh * NS + s;

    float xv[16];
    const float4* x4 = (const float4*)(x + (size_t)r * 16);
#pragma unroll
    for (int j = 0; j < 4; ++j) {
        float4 a = x4[j];
        xv[4*j] = a.x; xv[4*j+1] = a.y; xv[4*j+2] = a.z; xv[4*j+3] = a.w;
    }

    if (job < 4) {
        float* outb = ((job < 2) ? hq : hk) + (size_t)bh * 32768 + (size_t)(job & 1) * 16384;
        float h[32];
#pragma unroll
        for (int f = 0; f < 32; ++f) h[f] = c_s[f];
#pragma unroll
        for (int e = 0; e < 16; ++e)
#pragma unroll
            for (int f = 0; f < 32; ++f)
                h[f] = fmaf(xv[e], m_s[e * 32 + f], h[f]);
#pragma unroll
        for (int f = 0; f < 32; ++f)
            outb[(size_t)f * NS + s] = h[f];
    } else {
        float* outb = vpt + (size_t)bh * 8192;
        float h[16];
#pragma unroll
        for (int d = 0; d < 16; ++d) h[d] = c_s[d];
#pragma unroll
        for (int e = 0; e < 16; ++e)
#pragma unroll
            for (int d = 0; d < 16; ++d)
                h[d] = fmaf(xv[e], m_s[e * 32 + d], h[d]);
#pragma unroll
        for (int d = 0; d < 16; ++d)
            outb[(size_t)d * NS + s] = h[d];
    }
}

// ---------------- Kernel 2: fused scores + softmax + PV + Wo ----------------
// grid 256 = 8 bh x 32 q-tiles; 512 threads (8 waves). Thread owns one k.
__global__ __launch_bounds__(512) void k_fused(
    const float* __restrict__ hq, const float* __restrict__ hk,
    const float* __restrict__ vpt,
    const float* __restrict__ N2, const float* __restrict__ b2,
    const float* __restrict__ mask,
    const float* __restrict__ Wo, const float* __restrict__ bo,
    float* __restrict__ attn, float* __restrict__ out)
{
    __shared__ __align__(16) float hq_s[16 * 68];    // [qi][f], row = 17 float4
    __shared__ __align__(16) float attn_s[16 * 516]; // [qi][k], row = 129 float4
    __shared__ float wo_s[256];
    __shared__ float bo_s[16];
    __shared__ float ov_s[256];
    __shared__ float part_s[2304];                   // [qi*16+d][khalf], stride 9
    __shared__ float redm[128];                      // [qi][wave] max
    __shared__ float reds[128];                      // [qi][wave] sum

    const int bh  = blockIdx.x >> 5;
    const int q0  = (blockIdx.x & 31) << 4;
    const int tid = threadIdx.x;
    const int wave = tid >> 6, lane = tid & 63;
    const int k = tid;
    const size_t base = (size_t)bh * 32768;

    // ---- register loads ----
    float hkA_l[32], hkB_l[32], n2_l[32], mreg[16];
#pragma unroll
    for (int f = 0; f < 32; ++f) hkA_l[f] = hk[base + (size_t)f * NS + k];
#pragma unroll
    for (int f = 0; f < 32; ++f) hkB_l[f] = hk[base + (size_t)(32+f) * NS + k];
#pragma unroll
    for (int f = 0; f < 32; ++f) n2_l[f] = N2[f];
    const int b = bh >> 2;   // H = 4
    const float* mbase = mask + (size_t)b * NS * NS;
#pragma unroll
    for (int qi = 0; qi < 16; ++qi) mreg[qi] = mbase[(size_t)(q0 + qi) * NS + k];
    const float b2v = 2.0f * b2[0];

    // ---- LDS staging ----
    for (int i = tid; i < 1024; i += 512) {          // 16 qi x 64 f = 1024  ✓
        int f = i >> 4, qi = i & 15;
        hq_s[qi * 68 + f] = hq[base + (size_t)f * NS + q0 + qi];
    }
    if (tid < 256) wo_s[tid] = Wo[tid];
    if (tid < 16)  bo_s[tid] = bo[tid];
    __syncthreads();

    // ---- phase 1: scores for all 16 qi, wave-level max reduce ----
    float sreg[16];
#pragma unroll
    for (int qi = 0; qi < 16; ++qi) {
        const float4* hq4 = (const float4*)&hq_s[qi * 68];
        float s0 = b2v, s1 = 0.f, s2 = 0.f, s3 = 0.f;
#pragma unroll
        for (int f4 = 0; f4 < 8; ++f4) {
            float4 ha = hq4[f4];       // hqA[f4*4 .. +3]
            float4 hb = hq4[8 + f4];   // hqB'[f4*4 .. +3]
            {
                const int f = 4*f4;
                float a = fmaxf(ha.x + hkB_l[f], 0.f) + fmaxf(hb.x + hkA_l[f], 0.f);
                s0 = fmaf(n2_l[f], a, s0);
            }
            {
                const int f = 4*f4 + 1;
                float a = fmaxf(ha.y + hkB_l[f], 0.f) + fmaxf(hb.y + hkA_l[f], 0.f);
                s1 = fmaf(n2_l[f], a, s1);
            }
            {
                const int f = 4*f4 + 2;
                float a = fmaxf(ha.z + hkB_l[f], 0.f) + fmaxf(hb.z + hkA_l[f], 0.f);
                s2 = fmaf(n2_l[f], a, s2);
            }
            {
                const int f = 4*f4 + 3;
                float a = fmaxf(ha.w + hkB_l[f], 0.f) + fmaxf(hb.w + hkA_l[f], 0.f);
                s3 = fmaf(n2_l[f], a, s3);
            }
        }
        float s = (s0 + s1) + (s2 + s3);
        s = fmaf(mreg[qi], -1e9f, s);
        sreg[qi] = s;

        float m = s;
#pragma unroll
        for (int off = 32; off > 0; off >>= 1) m = fmaxf(m, __shfl_xor(m, off));
        if (lane == 0) redm[qi * 8 + wave] = m;
    }
    __syncthreads();

    // ---- phase 2: block max, exp, wave-level sum reduce ----
    float preg[16];
#pragma unroll
    for (int qi = 0; qi < 16; ++qi) {
        float bm = redm[qi * 8];
#pragma unroll
        for (int w = 1; w < 8; ++w) bm = fmaxf(bm, redm[qi * 8 + w]);
        float e = __expf(sreg[qi] - bm);
        preg[qi] = e;
        float ss = e;
#pragma unroll
        for (int off = 32; off > 0; off >>= 1) ss += __shfl_xor(ss, off);
        if (lane == 0) reds[qi * 8 + wave] = ss;
    }
    __syncthreads();

    // ---- phase 3: normalize, write attn (global + LDS) ----
#pragma unroll
    for (int qi = 0; qi < 16; ++qi) {
        float tot = reds[qi * 8];
#pragma unroll
        for (int w = 1; w < 8; ++w) tot += reds[qi * 8 + w];
        float p = preg[qi] / tot;
        attn[(size_t)(bh * NS + q0 + qi) * NS + k] = p;
        attn_s[qi * 516 + k] = p;
    }
    __syncthreads();

    // ---- phase 4: PV. thread = (khalf = tid>>6, dgrp = (tid>>4)&3, qi = tid&15) ----
    {
        const int qi_p  = tid & 15;
        const int dgrp  = (tid >> 4) & 3;
        const int khalf = tid >> 6;                         // 0..7, k in [khalf*64, +64)
        const float4* a4 = (const float4*)attn_s;           // row stride 129
        const float4* v4 = (const float4*)(vpt + (size_t)bh * 8192); // [d][128]
        float acc0 = 0.f, acc1 = 0.f, acc2 = 0.f, acc3 = 0.f;
#pragma unroll
        for (int kq = 0; kq < 16; ++kq) {
            const int k4 = khalf * 16 + kq;                 // float4 idx, 0..127
            float4 av = a4[qi_p * 129 + k4];
            float4 w0 = v4[(dgrp * 4 + 0) * 128 + k4];
            float4 w1 = v4[(dgrp * 4 + 1) * 128 + k4];
            float4 w2 = v4[(dgrp * 4 + 2) * 128 + k4];
            float4 w3 = v4[(dgrp * 4 + 3) * 128 + k4];
            acc0 = fmaf(av.x, w0.x, fmaf(av.y, w0.y, fmaf(av.z, w0.z, fmaf(av.w, w0.w, acc0))));
            acc1 = fmaf(av.x, w1.x, fmaf(av.y, w1.y, fmaf(av.z, w1.z, fmaf(av.w, w1.w, acc1))));
            acc2 = fmaf(av.x, w2.x, fmaf(av.y, w2.y, fmaf(av.z, w2.z, fmaf(av.w, w2.w, acc2))));
            acc3 = fmaf(av.x, w3.x, fmaf(av.y, w3.y, fmaf(av.z, w3.z, fmaf(av.w, w3.w, acc3))));
        }
        part_s[(qi_p * 16 + dgrp * 4 + 0) * 9 + khalf] = acc0;
        part_s[(qi_p * 16 + dgrp * 4 + 1) * 9 + khalf] = acc1;
        part_s[(qi_p * 16 + dgrp * 4 + 2) * 9 + khalf] = acc2;
        part_s[(qi_p * 16 + dgrp * 4 + 3) * 9 + khalf] = acc3;
    }
    __syncthreads();

    // ---- phase 5: combine k-partials ----
    if (tid < 256) {
        const int qi2 = tid >> 4, d = tid & 15;
        float ov = 0.f;
#pragma unroll
        for (int kh = 0; kh < 8; ++kh) ov += part_s[(qi2 * 16 + d) * 9 + kh];
        ov_s[qi2 * 16 + d] = ov;
    }
    __syncthreads();

    // ---- phase 6: out = ov @ Wo + bo ----
    if (tid < 256) {
        const int qi2 = tid >> 4, d = tid & 15;
        float res = bo_s[d];
#pragma unroll
        for (int e = 0; e < 16; ++e)
            res = fmaf(ov_s[qi2 * 16 + e], wo_s[e * 16 + d], res);
        out[(size_t)(bh * NS + q0 + qi2) * 16 + d] = res;
    }
}

extern "C" void kernel_launch(void* const* d_in, const int* in_sizes, int n_in,
                              void* d_out, int out_size, void* d_ws, size_t ws_size,
                              hipStream_t stream)
{
    const float* v    = (const float*)d_in[0];
    const float* k    = (const float*)d_in[1];
    const float* q    = (const float*)d_in[2];
    const float* mask = (const float*)d_in[3];
    const float* Wq   = (const float*)d_in[4];
    const float* bq   = (const float*)d_in[5];
    const float* Wk   = (const float*)d_in[6];
    const float* bk   = (const float*)d_in[7];
    const float* Wv   = (const float*)d_in[8];
    const float* bv   = (const float*)d_in[9];
    const float* Wo   = (const float*)d_in[10];
    const float* bo   = (const float*)d_in[11];
    const float* N1   = (const float*)d_in[12];
    const float* b1   = (const float*)d_in[13];
    const float* N2   = (const float*)d_in[14];
    const float* b2   = (const float*)d_in[15];

    float* out  = (float*)d_out;                   // 65536 floats
    float* attn = out + (size_t)NB*NH*NS*ND;       // 2097152 floats

    float* hq  = (float*)d_ws;                     // 262144 floats
    float* hk  = hq + (size_t)8 * 32768;           // 262144 floats
    float* vpt = hk + (size_t)8 * 32768;           // 65536 floats

    k_proj <<<80, 256, 0, stream>>>(q, k, v, Wq, bq, Wk, bk, Wv, bv, N1, b1, hq, hk, vpt);
    k_fused<<<256, 512, 0, stream>>>(hq, hk, vpt, N2, b2, mask, Wo, bo, attn, out);
}

// Round 7
// 34.486 us; speedup vs baseline: 4.1833x; 1.1039x over previous
//
#include <hip/hip_runtime.h>

#define NB 2
#define NH 4
#define NS 512
#define ND 16
#define NF 32

typedef float v2f __attribute__((ext_vector_type(2)));

// workspace layouts:
//   hq, hk : [bh][f 0..63][s 0..511]   (f<32: @A part, f>=32: @B+b1 part)
//   vpt    : [bh][d 0..15][s 0..511]   (transposed vp)

// ---------------- Kernel 1: fused projections (unchanged) ----------------
__global__ __launch_bounds__(256) void k_proj(
    const float* __restrict__ q, const float* __restrict__ kin, const float* __restrict__ v,
    const float* __restrict__ Wq, const float* __restrict__ bq,
    const float* __restrict__ Wk, const float* __restrict__ bk,
    const float* __restrict__ Wv, const float* __restrict__ bv,
    const float* __restrict__ N1, const float* __restrict__ b1,
    float* __restrict__ hq, float* __restrict__ hk, float* __restrict__ vpt)
{
    __shared__ float m_s[16 * 32];
    __shared__ float c_s[32];

    const int bid = blockIdx.x;
    const int job = bid % 5;
    const int sc  = (bid / 5) & 1;
    const int bh  = bid / 10;
    const int t   = threadIdx.x;

    const float* W    = (job < 2) ? Wq : (job < 4 ? Wk : Wv);
    const float* bias = (job < 2) ? bq : (job < 4 ? bk : bv);
    const float* x    = (job < 2) ? q  : (job < 4 ? kin : v);

    if (job < 4) {
        const int noff = (job & 1) * 16;
        for (int i = t; i < 512; i += 256) {
            int e = i >> 5, f = i & 31;
            float m = 0.f;
#pragma unroll
            for (int d = 0; d < 16; ++d)
                m = fmaf(W[e * 16 + d], N1[(noff + d) * 32 + f], m);
            m_s[i] = m;
        }
        if (t < 32) {
            float c = (job & 1) ? b1[t] : 0.f;
#pragma unroll
            for (int d = 0; d < 16; ++d)
                c = fmaf(bias[d], N1[(noff + d) * 32 + t], c);
            c_s[t] = c;
        }
    } else {
        int e = t >> 4, d = t & 15;
        m_s[e * 32 + d] = W[e * 16 + d];
        if (t < 16) c_s[t] = bias[t];
    }
    __syncthreads();

    const int s = sc * 256 + t;
    const int r = bh * NS + s;

    float xv[16];
    const float4* x4 = (const float4*)(x + (size_t)r * 16);
#pragma unroll
    for (int j = 0; j < 4; ++j) {
        float4 a = x4[j];
        xv[4*j] = a.x; xv[4*j+1] = a.y; xv[4*j+2] = a.z; xv[4*j+3] = a.w;
    }

    if (job < 4) {
        float* outb = ((job < 2) ? hq : hk) + (size_t)bh * 32768 + (size_t)(job & 1) * 16384;
        float h[32];
#pragma unroll
        for (int f = 0; f < 32; ++f) h[f] = c_s[f];
#pragma unroll
        for (int e = 0; e < 16; ++e)
#pragma unroll
            for (int f = 0; f < 32; ++f)
                h[f] = fmaf(xv[e], m_s[e * 32 + f], h[f]);
#pragma unroll
        for (int f = 0; f < 32; ++f)
            outb[(size_t)f * NS + s] = h[f];
    } else {
        float* outb = vpt + (size_t)bh * 8192;
        float h[16];
#pragma unroll
        for (int d = 0; d < 16; ++d) h[d] = c_s[d];
#pragma unroll
        for (int e = 0; e < 16; ++e)
#pragma unroll
            for (int d = 0; d < 16; ++d)
                h[d] = fmaf(xv[e], m_s[e * 32 + d], h[d]);
#pragma unroll
        for (int d = 0; d < 16; ++d)
            outb[(size_t)d * NS + s] = h[d];
    }
}

// ---------------- Kernel 2: fused scores + softmax + PV + Wo ----------------
// grid 512 = 8 bh x 64 q-tiles (8 qi each); 512 threads (8 waves); thread owns one k.
// Packed f32 math (v_pk_*), register diet for 2 blocks/CU.
__global__ __launch_bounds__(512, 4) void k_fused(
    const float* __restrict__ hq, const float* __restrict__ hk,
    const float* __restrict__ vpt,
    const float* __restrict__ N2, const float* __restrict__ b2,
    const float* __restrict__ mask,
    const float* __restrict__ Wo, const float* __restrict__ bo,
    float* __restrict__ attn, float* __restrict__ out)
{
    __shared__ __align__(16) float hq_s[8 * 68];     // [qi][f], 16B-aligned rows
    __shared__ __align__(16) float attn_s[8 * 516];  // [qi][k], row = 129 float4
    __shared__ float wo_s[256];
    __shared__ float bo_s[16];
    __shared__ float ov_s[128];                      // [qi][d]
    __shared__ float part_s[128 * 17];               // [qi*16+d][koct 0..15], stride 17
    __shared__ float redm[64];                       // [qi][wave] max
    __shared__ float reds[64];                       // [qi][wave] sum

    const int bh  = blockIdx.x >> 6;
    const int q0  = (blockIdx.x & 63) << 3;
    const int tid = threadIdx.x;
    const int wave = tid >> 6, lane = tid & 63;
    const int k = tid;
    const size_t base = (size_t)bh * 32768;

    // ---- per-thread hk fragments (packed) + n2 ----
    v2f hk2A[16], hk2B[16], n2v[16];
#pragma unroll
    for (int f2 = 0; f2 < 16; ++f2) {
        hk2A[f2] = (v2f){ hk[base + (size_t)(2*f2    ) * NS + k],
                          hk[base + (size_t)(2*f2 + 1) * NS + k] };
        hk2B[f2] = (v2f){ hk[base + (size_t)(32 + 2*f2) * NS + k],
                          hk[base + (size_t)(33 + 2*f2) * NS + k] };
        n2v[f2]  = (v2f){ N2[2*f2], N2[2*f2 + 1] };
    }
    const float b2v = 2.0f * b2[0];
    const float* mbase = mask + (size_t)(bh >> 2) * NS * NS;   // H=4

    // ---- LDS staging: 8 qi x 64 f = 512 floats, one per thread ----
    {
        int f = tid >> 3, qi = tid & 7;
        hq_s[qi * 68 + f] = hq[base + (size_t)f * NS + q0 + qi];
    }
    if (tid < 256) wo_s[tid] = Wo[tid];
    if (tid < 16)  bo_s[tid] = bo[tid];
    __syncthreads();

    // ---- phase 1: scores for 8 qi (packed), wave max reduce ----
    float sreg[8];
    float mnext = mbase[(size_t)q0 * NS + k];
#pragma unroll
    for (int qi = 0; qi < 8; ++qi) {
        float mcur = mnext;
        if (qi < 7) mnext = mbase[(size_t)(q0 + qi + 1) * NS + k];
        const v2f* hq2 = (const v2f*)(hq_s + qi * 68);   // [0..15]=A, [16..31]=B
        v2f acc_a = 0.f, acc_b = 0.f;
        const v2f z = 0.f;
#pragma unroll
        for (int f2 = 0; f2 < 16; ++f2) {
            v2f t1 = hq2[f2]      + hk2B[f2];
            v2f t2 = hq2[16 + f2] + hk2A[f2];
            v2f r  = __builtin_elementwise_max(t1, z) + __builtin_elementwise_max(t2, z);
            if (f2 & 1) acc_b += n2v[f2] * r;
            else        acc_a += n2v[f2] * r;
        }
        v2f av = acc_a + acc_b;
        float s = av.x + av.y + b2v;
        s = fmaf(mcur, -1e9f, s);
        sreg[qi] = s;

        float m = s;
#pragma unroll
        for (int off = 32; off > 0; off >>= 1) m = fmaxf(m, __shfl_xor(m, off));
        if (lane == 0) redm[qi * 8 + wave] = m;
    }
    __syncthreads();

    // ---- phase 2: block max, exp, wave sum reduce ----
#pragma unroll
    for (int qi = 0; qi < 8; ++qi) {
        float bm = redm[qi * 8];
#pragma unroll
        for (int w = 1; w < 8; ++w) bm = fmaxf(bm, redm[qi * 8 + w]);
        float sm = sreg[qi] - bm;
        sreg[qi] = sm;                    // keep shifted score; recompute exp later
        float e = __expf(sm);
        float ss = e;
#pragma unroll
        for (int off = 32; off > 0; off >>= 1) ss += __shfl_xor(ss, off);
        if (lane == 0) reds[qi * 8 + wave] = ss;
    }
    __syncthreads();

    // ---- phase 3: normalize, write attn (global + LDS) ----
#pragma unroll
    for (int qi = 0; qi < 8; ++qi) {
        float tot = reds[qi * 8];
#pragma unroll
        for (int w = 1; w < 8; ++w) tot += reds[qi * 8 + w];
        float p = __expf(sreg[qi]) / tot;
        attn[(size_t)(bh * NS + q0 + qi) * NS + k] = p;
        attn_s[qi * 516 + k] = p;
    }
    __syncthreads();

    // ---- phase 4: PV. thread = (qi_p = tid&7, dgrp = (tid>>3)&3, koct = tid>>5) ----
    {
        const int qi_p = tid & 7;
        const int dgrp = (tid >> 3) & 3;
        const int koct = tid >> 5;                          // 0..15, 8 float4 each
        const float4* a4 = (const float4*)attn_s;           // row stride 129
        const float4* v4 = (const float4*)(vpt + (size_t)bh * 8192); // [d][128]
        float acc0 = 0.f, acc1 = 0.f, acc2 = 0.f, acc3 = 0.f;
#pragma unroll
        for (int kq = 0; kq < 8; ++kq) {
            const int k4 = koct * 8 + kq;
            float4 av = a4[qi_p * 129 + k4];
            float4 w0 = v4[(dgrp * 4 + 0) * 128 + k4];
            float4 w1 = v4[(dgrp * 4 + 1) * 128 + k4];
            float4 w2 = v4[(dgrp * 4 + 2) * 128 + k4];
            float4 w3 = v4[(dgrp * 4 + 3) * 128 + k4];
            acc0 = fmaf(av.x, w0.x, fmaf(av.y, w0.y, fmaf(av.z, w0.z, fmaf(av.w, w0.w, acc0))));
            acc1 = fmaf(av.x, w1.x, fmaf(av.y, w1.y, fmaf(av.z, w1.z, fmaf(av.w, w1.w, acc1))));
            acc2 = fmaf(av.x, w2.x, fmaf(av.y, w2.y, fmaf(av.z, w2.z, fmaf(av.w, w2.w, acc2))));
            acc3 = fmaf(av.x, w3.x, fmaf(av.y, w3.y, fmaf(av.z, w3.z, fmaf(av.w, w3.w, acc3))));
        }
        part_s[(qi_p * 16 + dgrp * 4 + 0) * 17 + koct] = acc0;
        part_s[(qi_p * 16 + dgrp * 4 + 1) * 17 + koct] = acc1;
        part_s[(qi_p * 16 + dgrp * 4 + 2) * 17 + koct] = acc2;
        part_s[(qi_p * 16 + dgrp * 4 + 3) * 17 + koct] = acc3;
    }
    __syncthreads();

    // ---- phase 5: combine k-partials (128 outputs) ----
    if (tid < 128) {
        float ov = 0.f;
#pragma unroll
        for (int kh = 0; kh < 16; ++kh) ov += part_s[tid * 17 + kh];
        ov_s[tid] = ov;
    }
    __syncthreads();

    // ---- phase 6: out = ov @ Wo + bo ----
    if (tid < 128) {
        const int qi2 = tid >> 4, d = tid & 15;
        float res = bo_s[d];
#pragma unroll
        for (int e = 0; e < 16; ++e)
            res = fmaf(ov_s[qi2 * 16 + e], wo_s[e * 16 + d], res);
        out[(size_t)(bh * NS + q0 + qi2) * 16 + d] = res;
    }
}

extern "C" void kernel_launch(void* const* d_in, const int* in_sizes, int n_in,
                              void* d_out, int out_size, void* d_ws, size_t ws_size,
                              hipStream_t stream)
{
    const float* v    = (const float*)d_in[0];
    const float* k    = (const float*)d_in[1];
    const float* q    = (const float*)d_in[2];
    const float* mask = (const float*)d_in[3];
    const float* Wq   = (const float*)d_in[4];
    const float* bq   = (const float*)d_in[5];
    const float* Wk   = (const float*)d_in[6];
    const float* bk   = (const float*)d_in[7];
    const float* Wv   = (const float*)d_in[8];
    const float* bv   = (const float*)d_in[9];
    const float* Wo   = (const float*)d_in[10];
    const float* bo   = (const float*)d_in[11];
    const float* N1   = (const float*)d_in[12];
    const float* b1   = (const float*)d_in[13];
    const float* N2   = (const float*)d_in[14];
    const float* b2   = (const float*)d_in[15];

    float* out  = (float*)d_out;                   // 65536 floats
    float* attn = out + (size_t)NB*NH*NS*ND;       // 2097152 floats

    float* hq  = (float*)d_ws;                     // 262144 floats
    float* hk  = hq + (size_t)8 * 32768;           // 262144 floats
    float* vpt = hk + (size_t)8 * 32768;           // 65536 floats

    k_proj <<<80, 256, 0, stream>>>(q, k, v, Wq, bq, Wk, bk, Wv, bv, N1, b1, hq, hk, vpt);
    k_fused<<<512, 512, 0, stream>>>(hq, hk, vpt, N2, b2, mask, Wo, bo, attn, out);
}

// Round 8
// 32.957 us; speedup vs baseline: 4.3773x; 1.0464x over previous
//
#include <hip/hip_runtime.h>

#define NB 2
#define NH 4
#define NS 512
#define ND 16
#define NF 32

typedef float v2f __attribute__((ext_vector_type(2)));

// workspace layouts:
//   hq_rm : [bh][s 0..511][f 0..63]  ROW-major (f<32: @A part, f>=32: @B+b1 part)
//   hk    : [bh][f 0..63][s 0..511]  transposed
//   vpt   : [bh][d 0..15][s 0..511]  transposed vp

// ---------------- Kernel 1: fused projections ----------------
// grid 80 = 8 bh * 2 s-chunks * 5 jobs; 256 threads.
// job 0/1: hq A/B half (row-major via LDS transpose); 2/3: hk A/B (transposed); 4: vpt.
__global__ __launch_bounds__(256) void k_proj(
    const float* __restrict__ q, const float* __restrict__ kin, const float* __restrict__ v,
    const float* __restrict__ Wq, const float* __restrict__ bq,
    const float* __restrict__ Wk, const float* __restrict__ bk,
    const float* __restrict__ Wv, const float* __restrict__ bv,
    const float* __restrict__ N1, const float* __restrict__ b1,
    float* __restrict__ hq_rm, float* __restrict__ hk, float* __restrict__ vpt)
{
    __shared__ float m_s[16 * 32];
    __shared__ float c_s[32];
    __shared__ float trans_s[256 * 33];   // [s_loc][f], pad 33 -> conflict-free

    const int bid = blockIdx.x;
    const int job = bid % 5;
    const int sc  = (bid / 5) & 1;
    const int bh  = bid / 10;
    const int t   = threadIdx.x;

    const float* W    = (job < 2) ? Wq : (job < 4 ? Wk : Wv);
    const float* bias = (job < 2) ? bq : (job < 4 ? bk : bv);
    const float* x    = (job < 2) ? q  : (job < 4 ? kin : v);

    if (job < 4) {
        const int noff = (job & 1) * 16;
        for (int i = t; i < 512; i += 256) {
            int e = i >> 5, f = i & 31;
            float m = 0.f;
#pragma unroll
            for (int d = 0; d < 16; ++d)
                m = fmaf(W[e * 16 + d], N1[(noff + d) * 32 + f], m);
            m_s[i] = m;
        }
        if (t < 32) {
            float c = (job & 1) ? b1[t] : 0.f;
#pragma unroll
            for (int d = 0; d < 16; ++d)
                c = fmaf(bias[d], N1[(noff + d) * 32 + t], c);
            c_s[t] = c;
        }
    } else {
        int e = t >> 4, d = t & 15;
        m_s[e * 32 + d] = W[e * 16 + d];
        if (t < 16) c_s[t] = bias[t];
    }
    __syncthreads();

    const int s = sc * 256 + t;
    const int r = bh * NS + s;

    float xv[16];
    const float4* x4 = (const float4*)(x + (size_t)r * 16);
#pragma unroll
    for (int j = 0; j < 4; ++j) {
        float4 a = x4[j];
        xv[4*j] = a.x; xv[4*j+1] = a.y; xv[4*j+2] = a.z; xv[4*j+3] = a.w;
    }

    if (job < 2) {
        // hq half: compute h[32], LDS-transpose, write row-major full lines
        float h[32];
#pragma unroll
        for (int f = 0; f < 32; ++f) h[f] = c_s[f];
#pragma unroll
        for (int e = 0; e < 16; ++e)
#pragma unroll
            for (int f = 0; f < 32; ++f)
                h[f] = fmaf(xv[e], m_s[e * 32 + f], h[f]);
#pragma unroll
        for (int f = 0; f < 32; ++f) trans_s[t * 33 + f] = h[f];
        __syncthreads();
        float* outb = hq_rm + (((size_t)(bh * NS + sc * 256)) << 6) + (job & 1) * 32;
#pragma unroll
        for (int it = 0; it < 32; ++it) {
            int j = it * 256 + t;            // 0..8191 = 256 s x 32 f
            int sl = j >> 5, f = j & 31;
            outb[((size_t)sl << 6) + f] = trans_s[sl * 33 + f];
        }
    } else if (job < 4) {
        float* outb = hk + (size_t)bh * 32768 + (size_t)(job & 1) * 16384;
        float h[32];
#pragma unroll
        for (int f = 0; f < 32; ++f) h[f] = c_s[f];
#pragma unroll
        for (int e = 0; e < 16; ++e)
#pragma unroll
            for (int f = 0; f < 32; ++f)
                h[f] = fmaf(xv[e], m_s[e * 32 + f], h[f]);
#pragma unroll
        for (int f = 0; f < 32; ++f)
            outb[(size_t)f * NS + s] = h[f];
    } else {
        float* outb = vpt + (size_t)bh * 8192;
        float h[16];
#pragma unroll
        for (int d = 0; d < 16; ++d) h[d] = c_s[d];
#pragma unroll
        for (int e = 0; e < 16; ++e)
#pragma unroll
            for (int d = 0; d < 16; ++d)
                h[d] = fmaf(xv[e], m_s[e * 32 + d], h[d]);
#pragma unroll
        for (int d = 0; d < 16; ++d)
            outb[(size_t)d * NS + s] = h[d];
    }
}

// ---------------- Kernel 2: fused scores + softmax + PV + Wo ----------------
// grid 512 = 8 bh x 64 q-tiles (8 qi); 512 threads (8 waves); thread owns one k.
// hq row read from UNIFORM global address -> scalar (SGPR) loads, no LDS in hot loop.
__global__ __launch_bounds__(512, 4) void k_fused(
    const float* __restrict__ hq_rm, const float* __restrict__ hk,
    const float* __restrict__ vpt,
    const float* __restrict__ N2, const float* __restrict__ b2,
    const float* __restrict__ mask,
    const float* __restrict__ Wo, const float* __restrict__ bo,
    float* __restrict__ attn, float* __restrict__ out)
{
    __shared__ __align__(16) float attn_s[8 * 516];  // [qi][k], row = 129 float4
    __shared__ float wo_s[256];
    __shared__ float bo_s[16];
    __shared__ float ov_s[128];                      // [qi][d]
    __shared__ float part_s[128 * 17];               // [qi*16+d][koct], stride 17
    __shared__ float redm[64];                       // [qi][wave] max
    __shared__ float reds[64];                       // [qi][wave] sum

    const int bh  = blockIdx.x >> 6;
    const int q0  = (blockIdx.x & 63) << 3;
    const int tid = threadIdx.x;
    const int wave = tid >> 6, lane = tid & 63;
    const int k = tid;
    const size_t base = (size_t)bh * 32768;

    // ---- per-thread hk fragments (packed) + n2 ----
    v2f hk2A[16], hk2B[16], n2v[16];
#pragma unroll
    for (int f2 = 0; f2 < 16; ++f2) {
        hk2A[f2] = (v2f){ hk[base + (size_t)(2*f2    ) * NS + k],
                          hk[base + (size_t)(2*f2 + 1) * NS + k] };
        hk2B[f2] = (v2f){ hk[base + (size_t)(32 + 2*f2) * NS + k],
                          hk[base + (size_t)(33 + 2*f2) * NS + k] };
        n2v[f2]  = (v2f){ N2[2*f2], N2[2*f2 + 1] };
    }
    const float b2v = 2.0f * b2[0];
    const float* mbase = mask + (size_t)(bh >> 2) * NS * NS;   // H=4

    if (tid < 256) wo_s[tid] = Wo[tid];
    if (tid < 16)  bo_s[tid] = bo[tid];
    __syncthreads();

    // ---- phase 1: scores for 8 qi; hq row via uniform (scalar) loads ----
    float sreg[8];
    float mnext = mbase[(size_t)q0 * NS + k];
#pragma unroll
    for (int qi = 0; qi < 8; ++qi) {
        float mcur = mnext;
        if (qi < 7) mnext = mbase[(size_t)(q0 + qi + 1) * NS + k];
        const v2f* hq2 = (const v2f*)(hq_rm + (((size_t)(bh * NS + q0 + qi)) << 6));
        v2f acc_a = 0.f, acc_b = 0.f;
        const v2f z = 0.f;
#pragma unroll
        for (int f2 = 0; f2 < 16; ++f2) {
            v2f t1 = hq2[f2]      + hk2B[f2];   // A(q) + B'(k)
            v2f t2 = hq2[16 + f2] + hk2A[f2];   // B'(q) + A(k)
            v2f r  = __builtin_elementwise_max(t1, z) + __builtin_elementwise_max(t2, z);
            if (f2 & 1) acc_b += n2v[f2] * r;
            else        acc_a += n2v[f2] * r;
        }
        v2f av = acc_a + acc_b;
        float s = av.x + av.y + b2v;
        s = fmaf(mcur, -1e9f, s);
        sreg[qi] = s;

        float m = s;
#pragma unroll
        for (int off = 32; off > 0; off >>= 1) m = fmaxf(m, __shfl_xor(m, off));
        if (lane == 0) redm[qi * 8 + wave] = m;
    }
    __syncthreads();

    // ---- phase 2: block max, exp, wave sum reduce ----
    float preg[8];
#pragma unroll
    for (int qi = 0; qi < 8; ++qi) {
        float bm = redm[qi * 8];
#pragma unroll
        for (int w = 1; w < 8; ++w) bm = fmaxf(bm, redm[qi * 8 + w]);
        float e = __expf(sreg[qi] - bm);
        preg[qi] = e;
        float ss = e;
#pragma unroll
        for (int off = 32; off > 0; off >>= 1) ss += __shfl_xor(ss, off);
        if (lane == 0) reds[qi * 8 + wave] = ss;
    }
    __syncthreads();

    // ---- phase 3: normalize, write attn (global + LDS) ----
#pragma unroll
    for (int qi = 0; qi < 8; ++qi) {
        float tot = reds[qi * 8];
#pragma unroll
        for (int w = 1; w < 8; ++w) tot += reds[qi * 8 + w];
        float p = preg[qi] / tot;
        attn[(size_t)(bh * NS + q0 + qi) * NS + k] = p;
        attn_s[qi * 516 + k] = p;
    }
    __syncthreads();

    // ---- phase 4: PV. thread = (qi_p = tid&7, dgrp = (tid>>3)&3, koct = tid>>5) ----
    {
        const int qi_p = tid & 7;
        const int dgrp = (tid >> 3) & 3;
        const int koct = tid >> 5;                          // 0..15, 8 float4 each
        const float4* a4 = (const float4*)attn_s;           // row stride 129
        const float4* v4 = (const float4*)(vpt + (size_t)bh * 8192); // [d][128]
        float acc0 = 0.f, acc1 = 0.f, acc2 = 0.f, acc3 = 0.f;
#pragma unroll
        for (int kq = 0; kq < 8; ++kq) {
            const int k4 = koct * 8 + kq;
            float4 av = a4[qi_p * 129 + k4];
            float4 w0 = v4[(dgrp * 4 + 0) * 128 + k4];
            float4 w1 = v4[(dgrp * 4 + 1) * 128 + k4];
            float4 w2 = v4[(dgrp * 4 + 2) * 128 + k4];
            float4 w3 = v4[(dgrp * 4 + 3) * 128 + k4];
            acc0 = fmaf(av.x, w0.x, fmaf(av.y, w0.y, fmaf(av.z, w0.z, fmaf(av.w, w0.w, acc0))));
            acc1 = fmaf(av.x, w1.x, fmaf(av.y, w1.y, fmaf(av.z, w1.z, fmaf(av.w, w1.w, acc1))));
            acc2 = fmaf(av.x, w2.x, fmaf(av.y, w2.y, fmaf(av.z, w2.z, fmaf(av.w, w2.w, acc2))));
            acc3 = fmaf(av.x, w3.x, fmaf(av.y, w3.y, fmaf(av.z, w3.z, fmaf(av.w, w3.w, acc3))));
        }
        part_s[(qi_p * 16 + dgrp * 4 + 0) * 17 + koct] = acc0;
        part_s[(qi_p * 16 + dgrp * 4 + 1) * 17 + koct] = acc1;
        part_s[(qi_p * 16 + dgrp * 4 + 2) * 17 + koct] = acc2;
        part_s[(qi_p * 16 + dgrp * 4 + 3) * 17 + koct] = acc3;
    }
    __syncthreads();

    // ---- phase 5: combine k-partials (128 outputs) ----
    if (tid < 128) {
        float ov = 0.f;
#pragma unroll
        for (int kh = 0; kh < 16; ++kh) ov += part_s[tid * 17 + kh];
        ov_s[tid] = ov;
    }
    __syncthreads();

    // ---- phase 6: out = ov @ Wo + bo ----
    if (tid < 128) {
        const int qi2 = tid >> 4, d = tid & 15;
        float res = bo_s[d];
#pragma unroll
        for (int e = 0; e < 16; ++e)
            res = fmaf(ov_s[qi2 * 16 + e], wo_s[e * 16 + d], res);
        out[(size_t)(bh * NS + q0 + qi2) * 16 + d] = res;
    }
}

extern "C" void kernel_launch(void* const* d_in, const int* in_sizes, int n_in,
                              void* d_out, int out_size, void* d_ws, size_t ws_size,
                              hipStream_t stream)
{
    const float* v    = (const float*)d_in[0];
    const float* k    = (const float*)d_in[1];
    const float* q    = (const float*)d_in[2];
    const float* mask = (const float*)d_in[3];
    const float* Wq   = (const float*)d_in[4];
    const float* bq   = (const float*)d_in[5];
    const float* Wk   = (const float*)d_in[6];
    const float* bk   = (const float*)d_in[7];
    const float* Wv   = (const float*)d_in[8];
    const float* bv   = (const float*)d_in[9];
    const float* Wo   = (const float*)d_in[10];
    const float* bo   = (const float*)d_in[11];
    const float* N1   = (const float*)d_in[12];
    const float* b1   = (const float*)d_in[13];
    const float* N2   = (const float*)d_in[14];
    const float* b2   = (const float*)d_in[15];

    float* out  = (float*)d_out;                   // 65536 floats
    float* attn = out + (size_t)NB*NH*NS*ND;       // 2097152 floats

    float* hq_rm = (float*)d_ws;                   // 262144 floats
    float* hk    = hq_rm + (size_t)8 * 32768;      // 262144 floats
    float* vpt   = hk + (size_t)8 * 32768;         // 65536 floats

    k_proj <<<80, 256, 0, stream>>>(q, k, v, Wq, bq, Wk, bk, Wv, bv, N1, b1, hq_rm, hk, vpt);
    k_fused<<<512, 512, 0, stream>>>(hq_rm, hk, vpt, N2, b2, mask, Wo, bo, attn, out);
}

// Round 9
// 32.142 us; speedup vs baseline: 4.4884x; 1.0254x over previous
//
#include <hip/hip_runtime.h>

#define NB 2
#define NH 4
#define NS 512
#define ND 16
#define NF 32

typedef float v4f __attribute__((ext_vector_type(4)));

// workspace layouts:
//   hq_rm : [bh][s 0..511][f 0..63]  row-major (f<32: @A, f>=32: @B+b1) -- float4-aligned rows
//   hkp   : [bh][half(A=0,B=1)][f4 0..7][s 0..511][c 0..3]  paired-x4
//   vpt   : [bh][d 0..15][s 0..511]

// ---------------- Kernel 1: fused projections ----------------
// grid 80 = 8 bh * 2 s-chunks * 5 jobs; 256 threads.
// job 0/1: hq A/B half (row-major via LDS transpose); 2/3: hk A/B (paired-x4 via LDS transpose); 4: vpt.
__global__ __launch_bounds__(256) void k_proj(
    const float* __restrict__ q, const float* __restrict__ kin, const float* __restrict__ v,
    const float* __restrict__ Wq, const float* __restrict__ bq,
    const float* __restrict__ Wk, const float* __restrict__ bk,
    const float* __restrict__ Wv, const float* __restrict__ bv,
    const float* __restrict__ N1, const float* __restrict__ b1,
    float* __restrict__ hq_rm, float* __restrict__ hkp, float* __restrict__ vpt)
{
    __shared__ float m_s[16 * 32];
    __shared__ float c_s[32];
    __shared__ float trans_s[256 * 33];   // [s_loc][f 0..31]

    const int bid = blockIdx.x;
    const int job = bid % 5;
    const int sc  = (bid / 5) & 1;
    const int bh  = bid / 10;
    const int t   = threadIdx.x;

    const float* W    = (job < 2) ? Wq : (job < 4 ? Wk : Wv);
    const float* bias = (job < 2) ? bq : (job < 4 ? bk : bv);
    const float* x    = (job < 2) ? q  : (job < 4 ? kin : v);

    if (job < 4) {
        const int noff = (job & 1) * 16;
        for (int i = t; i < 512; i += 256) {
            int e = i >> 5, f = i & 31;
            float m = 0.f;
#pragma unroll
            for (int d = 0; d < 16; ++d)
                m = fmaf(W[e * 16 + d], N1[(noff + d) * 32 + f], m);
            m_s[i] = m;
        }
        if (t < 32) {
            float c = (job & 1) ? b1[t] : 0.f;
#pragma unroll
            for (int d = 0; d < 16; ++d)
                c = fmaf(bias[d], N1[(noff + d) * 32 + t], c);
            c_s[t] = c;
        }
    } else {
        int e = t >> 4, d = t & 15;
        m_s[e * 32 + d] = W[e * 16 + d];
        if (t < 16) c_s[t] = bias[t];
    }
    __syncthreads();

    const int s = sc * 256 + t;
    const int r = bh * NS + s;

    float xv[16];
    const float4* x4 = (const float4*)(x + (size_t)r * 16);
#pragma unroll
    for (int j = 0; j < 4; ++j) {
        float4 a = x4[j];
        xv[4*j] = a.x; xv[4*j+1] = a.y; xv[4*j+2] = a.z; xv[4*j+3] = a.w;
    }

    if (job < 4) {
        float h[32];
#pragma unroll
        for (int f = 0; f < 32; ++f) h[f] = c_s[f];
#pragma unroll
        for (int e = 0; e < 16; ++e)
#pragma unroll
            for (int f = 0; f < 32; ++f)
                h[f] = fmaf(xv[e], m_s[e * 32 + f], h[f]);
#pragma unroll
        for (int f = 0; f < 32; ++f) trans_s[t * 33 + f] = h[f];
        __syncthreads();

        if (job < 2) {
            // hq row-major: row s, half (job&1)
            float* outb = hq_rm + (((size_t)(bh * NS + sc * 256)) << 6) + (job & 1) * 32;
#pragma unroll
            for (int it = 0; it < 32; ++it) {
                int j = it * 256 + t;            // 0..8191 = 256 s x 32 f
                int sl = j >> 5, f = j & 31;
                outb[((size_t)sl << 6) + f] = trans_s[sl * 33 + f];
            }
        } else {
            // hk paired-x4: [half][f4][s][c]
            float* outb = hkp + (size_t)bh * 32768 + (size_t)(job & 1) * 16384 + sc * 1024;
#pragma unroll
            for (int it = 0; it < 32; ++it) {
                int i = it * 256 + t;            // 0..8191 = 8 f4 x 256 s x 4 c
                int f4 = i >> 10, rem = i & 1023;
                int sl = rem >> 2, c = rem & 3;
                outb[(size_t)f4 * 2048 + rem] = trans_s[sl * 33 + f4 * 4 + c];
            }
        }
    } else {
        float* outb = vpt + (size_t)bh * 8192;
        float h[16];
#pragma unroll
        for (int d = 0; d < 16; ++d) h[d] = c_s[d];
#pragma unroll
        for (int e = 0; e < 16; ++e)
#pragma unroll
            for (int d = 0; d < 16; ++d)
                h[d] = fmaf(xv[e], m_s[e * 32 + d], h[d]);
#pragma unroll
        for (int d = 0; d < 16; ++d)
            outb[(size_t)d * NS + s] = h[d];
    }
}

// ---------------- Kernel 2: fused scores + softmax + PV + Wo ----------------
// grid 512 = 8 bh x 64 q-tiles (8 qi); 512 threads (8 waves); thread owns one k.
__global__ __launch_bounds__(512, 4) void k_fused(
    const float* __restrict__ hq_rm, const float* __restrict__ hkp,
    const float* __restrict__ vpt,
    const float* __restrict__ N2, const float* __restrict__ b2,
    const float* __restrict__ mask,
    const float* __restrict__ Wo, const float* __restrict__ bo,
    float* __restrict__ attn, float* __restrict__ out)
{
    __shared__ __align__(16) float attn_s[8 * 516];  // [qi][k]
    __shared__ float wo_s[256];
    __shared__ float bo_s[16];
    __shared__ float ov_s[128];                      // [qi][d]
    __shared__ float part_s[128 * 17];               // [qi*16+d][koct]
    __shared__ float redm[64];                       // [qi][wave] max
    __shared__ float reds[64];                       // [qi][wave] sum(exp(s-m_w))

    const int bh  = blockIdx.x >> 6;
    const int q0  = (blockIdx.x & 63) << 3;
    const int tid = threadIdx.x;
    const int wave = tid >> 6, lane = tid & 63;
    const int k = tid;
    const size_t base = (size_t)bh * 32768;

    // ---- per-thread hk fragments: 16 coalesced float4 loads ----
    v4f hkA4[8], hkB4[8];
    const v4f* hkb = (const v4f*)(hkp + base + (size_t)k * 4);   // stride per f4 = 2048 floats = 512 v4f
#pragma unroll
    for (int f4 = 0; f4 < 8; ++f4) hkA4[f4] = hkb[f4 * 512];
#pragma unroll
    for (int f4 = 0; f4 < 8; ++f4) hkB4[f4] = hkb[4096 + f4 * 512];

    // n2 as uniform (scalar) values packed to v4f
    v4f n24[8];
#pragma unroll
    for (int f4 = 0; f4 < 8; ++f4)
        n24[f4] = (v4f){ N2[4*f4], N2[4*f4+1], N2[4*f4+2], N2[4*f4+3] };
    const float b2v = 2.0f * b2[0];

    // mask prefetch (8 rows)
    const float* mbase = mask + (size_t)(bh >> 2) * NS * NS;   // H=4
    float mreg[8];
#pragma unroll
    for (int qi = 0; qi < 8; ++qi) mreg[qi] = mbase[(size_t)(q0 + qi) * NS + k];

    if (tid < 256) wo_s[tid] = Wo[tid];
    if (tid < 16)  bo_s[tid] = bo[tid];
    __syncthreads();

    // ---- phase 1: scores; per-wave max AND per-wave exp-sum ----
    float sreg[8];   // s - m_w (wave-shifted)
#pragma unroll
    for (int qi = 0; qi < 8; ++qi) {
        const v4f* hq4 = (const v4f*)(hq_rm + (((size_t)(bh * NS + q0 + qi)) << 6)); // uniform -> s_load
        v4f acc = 0.f;
        const v4f z = 0.f;
#pragma unroll
        for (int f4 = 0; f4 < 8; ++f4) {
            v4f t1 = hq4[f4]     + hkB4[f4];   // A(q) + B'(k)
            v4f t2 = hq4[8 + f4] + hkA4[f4];   // B'(q) + A(k)
            v4f rr = __builtin_elementwise_max(t1, z) + __builtin_elementwise_max(t2, z);
            acc += n24[f4] * rr;
        }
        float s = (acc.x + acc.y) + (acc.z + acc.w) + b2v;
        s = fmaf(mreg[qi], -1e9f, s);

        float m = s;
#pragma unroll
        for (int off = 32; off > 0; off >>= 1) m = fmaxf(m, __shfl_xor(m, off));
        float e = __expf(s - m);
        sreg[qi] = s - m;
        float ss = e;
#pragma unroll
        for (int off = 32; off > 0; off >>= 1) ss += __shfl_xor(ss, off);
        if (lane == 0) { redm[qi * 8 + wave] = m; reds[qi * 8 + wave] = ss; }
    }
    __syncthreads();

    // ---- phase 2+3: block combine, normalize, write attn ----
#pragma unroll
    for (int qi = 0; qi < 8; ++qi) {
        float M = redm[qi * 8];
#pragma unroll
        for (int w = 1; w < 8; ++w) M = fmaxf(M, redm[qi * 8 + w]);
        float tot = 0.f;
#pragma unroll
        for (int w = 0; w < 8; ++w)
            tot = fmaf(reds[qi * 8 + w], __expf(redm[qi * 8 + w] - M), tot);
        float mw = redm[qi * 8 + wave];
        float p = __expf(sreg[qi] + (mw - M)) * __builtin_amdgcn_rcpf(tot);
        attn[(size_t)(bh * NS + q0 + qi) * NS + k] = p;
        attn_s[qi * 516 + k] = p;
    }
    __syncthreads();

    // ---- phase 4: PV. thread = (qi_p = tid&7, dgrp = (tid>>3)&3, koct = tid>>5) ----
    {
        const int qi_p = tid & 7;
        const int dgrp = (tid >> 3) & 3;
        const int koct = tid >> 5;                          // 0..15, 8 float4 each
        const float4* a4 = (const float4*)attn_s;           // row stride 129
        const float4* v4 = (const float4*)(vpt + (size_t)bh * 8192); // [d][128]
        float acc0 = 0.f, acc1 = 0.f, acc2 = 0.f, acc3 = 0.f;
#pragma unroll
        for (int kq = 0; kq < 8; ++kq) {
            const int k4 = koct * 8 + kq;
            float4 av = a4[qi_p * 129 + k4];
            float4 w0 = v4[(dgrp * 4 + 0) * 128 + k4];
            float4 w1 = v4[(dgrp * 4 + 1) * 128 + k4];
            float4 w2 = v4[(dgrp * 4 + 2) * 128 + k4];
            float4 w3 = v4[(dgrp * 4 + 3) * 128 + k4];
            acc0 = fmaf(av.x, w0.x, fmaf(av.y, w0.y, fmaf(av.z, w0.z, fmaf(av.w, w0.w, acc0))));
            acc1 = fmaf(av.x, w1.x, fmaf(av.y, w1.y, fmaf(av.z, w1.z, fmaf(av.w, w1.w, acc1))));
            acc2 = fmaf(av.x, w2.x, fmaf(av.y, w2.y, fmaf(av.z, w2.z, fmaf(av.w, w2.w, acc2))));
            acc3 = fmaf(av.x, w3.x, fmaf(av.y, w3.y, fmaf(av.z, w3.z, fmaf(av.w, w3.w, acc3))));
        }
        part_s[(qi_p * 16 + dgrp * 4 + 0) * 17 + koct] = acc0;
        part_s[(qi_p * 16 + dgrp * 4 + 1) * 17 + koct] = acc1;
        part_s[(qi_p * 16 + dgrp * 4 + 2) * 17 + koct] = acc2;
        part_s[(qi_p * 16 + dgrp * 4 + 3) * 17 + koct] = acc3;
    }
    __syncthreads();

    // ---- phase 5: combine k-partials ----
    if (tid < 128) {
        float ov = 0.f;
#pragma unroll
        for (int kh = 0; kh < 16; ++kh) ov += part_s[tid * 17 + kh];
        ov_s[tid] = ov;
    }
    __syncthreads();

    // ---- phase 6: out = ov @ Wo + bo ----
    if (tid < 128) {
        const int qi2 = tid >> 4, d = tid & 15;
        float res = bo_s[d];
#pragma unroll
        for (int e = 0; e < 16; ++e)
            res = fmaf(ov_s[qi2 * 16 + e], wo_s[e * 16 + d], res);
        out[(size_t)(bh * NS + q0 + qi2) * 16 + d] = res;
    }
}

extern "C" void kernel_launch(void* const* d_in, const int* in_sizes, int n_in,
                              void* d_out, int out_size, void* d_ws, size_t ws_size,
                              hipStream_t stream)
{
    const float* v    = (const float*)d_in[0];
    const float* k    = (const float*)d_in[1];
    const float* q    = (const float*)d_in[2];
    const float* mask = (const float*)d_in[3];
    const float* Wq   = (const float*)d_in[4];
    const float* bq   = (const float*)d_in[5];
    const float* Wk   = (const float*)d_in[6];
    const float* bk   = (const float*)d_in[7];
    const float* Wv   = (const float*)d_in[8];
    const float* bv   = (const float*)d_in[9];
    const float* Wo   = (const float*)d_in[10];
    const float* bo   = (const float*)d_in[11];
    const float* N1   = (const float*)d_in[12];
    const float* b1   = (const float*)d_in[13];
    const float* N2   = (const float*)d_in[14];
    const float* b2   = (const float*)d_in[15];

    float* out  = (float*)d_out;                   // 65536 floats
    float* attn = out + (size_t)NB*NH*NS*ND;       // 2097152 floats

    float* hq_rm = (float*)d_ws;                   // 262144 floats
    float* hkp   = hq_rm + (size_t)8 * 32768;      // 262144 floats
    float* vpt   = hkp + (size_t)8 * 32768;        // 65536 floats

    k_proj <<<80, 256, 0, stream>>>(q, k, v, Wq, bq, Wk, bk, Wv, bv, N1, b1, hq_rm, hkp, vpt);
    k_fused<<<512, 512, 0, stream>>>(hq_rm, hkp, vpt, N2, b2, mask, Wo, bo, attn, out);
}